// Round 8
// baseline (151.881 us; speedup 1.0000x reference)
//
#include <hip/hip_runtime.h>
#include <stdint.h>

typedef __attribute__((ext_vector_type(8))) __bf16 bf16x8;
typedef __attribute__((ext_vector_type(16))) float f32x16;
typedef __attribute__((ext_vector_type(4))) unsigned int u32x4;
typedef __attribute__((ext_vector_type(4))) float f32x4;
typedef unsigned int u32;
typedef unsigned short u16;

#define THETA 0.7f

__host__ __device__ constexpr float pht_val(int q) {
  return (q == 12) ? (-4.0f + 1e-6f)
       : (q == 7 || q == 11 || q == 13 || q == 17) ? (1.0f + 1e-6f)
       : 1e-6f;
}

__device__ __forceinline__ u16 f2bf(float v) {
  u32 u = __builtin_bit_cast(u32, v);
  return (u16)((u + 0x7fffu + ((u >> 16) & 1u)) >> 16);
}

// ---------------- kernel 1: build K_eff, packed as MFMA A-fragments -------
__global__ __launch_bounds__(256) void k_prep(const float* __restrict__ wgt,
                                              const float* __restrict__ alpha,
                                              u16* __restrict__ apack) {
  int t = blockIdx.x * 256 + threadIdx.x;   // 4096 threads: (o, ci)
  int o = t >> 6, ci = t & 63;
  const float* wp = wgt + ((size_t)(o * 64 + ci)) * 25;
  float wv[25], sumw = 0.f;
#pragma unroll
  for (int p = 0; p < 25; ++p) { wv[p] = wp[p]; sumw += wv[p]; }
  float keff[25];
#pragma unroll
  for (int p = 0; p < 25; ++p) keff[p] = pht_val(p) * wv[p];  // a=0 (identity)
  constexpr int TP[33] = {0,1,2,3,4,6,7,9,12,13,  0,1,2,3,4,  0, 0, 0,
                          0,5,10,15,20,  0,5,6,10,11,12,15,17,20,21};
  constexpr int TQ[33] = {5,6,12,17,23,10,16,22,20,21,  0,5,10,15,20,  5, 0, 5,
                          0,6,7,8,9,  5,6,2,12,8,4,17,9,23,14};
#pragma unroll
  for (int e = 0; e < 33; ++e) keff[TP[e]] += pht_val(TQ[e]) * wv[TQ[e]];

  float al = alpha[0];
  int kc = ci >> 4, oh = o >> 5;
  int lane = ((ci >> 3) & 1) * 32 + (o & 31);   // A-frag: lane=(k/8)*32+m
#pragma unroll
  for (int p = 0; p < 25; ++p) {
    float v = al * (keff[p] * 0.125f);
    if (p == 12) v -= THETA * sumw;             // fold 1x1 branch into center
    size_t idx = ((((size_t)p * 4 + kc) * 2 + oh) * 64 + lane) * 8 + (ci & 7);
    apack[idx] = f2bf(v);
  }
}

// ---------------- kernel 2: x (NCHW fp32) -> X_t[n][y][px][i] bf16 --------
__global__ __launch_bounds__(256) void k_xcast(const float* __restrict__ x,
                                               u16* __restrict__ xt) {
  __shared__ u16 lt[64][130];
  int bid = blockIdx.x;                       // n*128 + y
  int n = bid >> 7, y = bid & 127;
  const float* xb = x + (size_t)n * 64 * 16384 + (size_t)y * 128;
  int t = threadIdx.x;
#pragma unroll
  for (int it = 0; it < 8; ++it) {            // float4 reads
    int idx = it * 256 + t;
    int i = idx >> 5, p4 = (idx & 31) * 4;
    f32x4 v = *(const f32x4*)(xb + (size_t)i * 16384 + p4);
    lt[i][p4 + 0] = f2bf(v.x); lt[i][p4 + 1] = f2bf(v.y);
    lt[i][p4 + 2] = f2bf(v.z); lt[i][p4 + 3] = f2bf(v.w);
  }
  __syncthreads();
  u32* xtb = (u32*)(xt + (size_t)(n * 128 + y) * 8192);
#pragma unroll
  for (int it = 0; it < 16; ++it) {           // u32 writes (2 i per lane)
    int idx = it * 256 + t;
    int px = idx >> 5, i2 = idx & 31;
    u32 w = (u32)lt[2 * i2][px] | ((u32)lt[2 * i2 + 1][px] << 16);
    xtb[(size_t)px * 32 + i2] = w;
  }
}

// ---------------- kernel 3: conv via 32x32x16 bf16 MFMA -------------------
// R6 geometry (4 rows x 64 px x 64 o, 72 KB tile, 2 blocks/CU) but 512
// threads = 8 waves = (oh, q32, rp row-pair). Per wave: 2 out rows, 2 accs;
// per (dx,kc): 6 ds_read_b128 + 5 A-loads -> 10 MFMAs. VGPR ~100 <= 128 so
// 2 blocks x 8 waves = 16 waves/CU = 4 waves/SIMD (2x the latency hiding
// of R6; occupancy was the R6 limit, MfmaUtil 44% at 2 waves/SIMD).
#define ROWB 9216

__global__ __launch_bounds__(512, 4) void k_conv(const u16* __restrict__ xt,
                                                 const u32x4* __restrict__ apv,
                                                 float* __restrict__ out) {
  __shared__ char tile[8 * ROWB];             // 73728 B
  int bid = blockIdx.x;
  int lg = (bid & 7) * 256 + (bid >> 3);      // XCD swizzle (2048%8==0)
  int ph = lg & 1, yt = (lg >> 1) & 31, n = lg >> 6;
  int y0 = yt * 4, px0 = ph * 64;
  int tid = threadIdx.x;
  int l = tid & 63, wv = tid >> 6;            // 8 waves

  // ---- stage: wave wv stages tile row wv (pre-swizzled source) ----
  {
    int r = wv;
    int sy = y0 + r - 2;
    char* rowbase = tile + r * ROWB;
    if ((unsigned)sy < 128u) {
      // row byte base shifted so tile col c holds src px = px0 + c - 2
      const char* xrow = (const char*)xt + ((size_t)(n * 128 + sy) * 16384)
                         + (ptrdiff_t)(px0 - 2) * 128;
      int g = l & 7;
#pragma unroll
      for (int it = 0; it < 9; ++it) {        // 576 granule slots >= 544+pad
        int gi = it * 64 + l;
        int c = gi >> 3;
        bool valid = ((unsigned)(px0 + c - 2) < 128u) && (c < 68);
        if (valid) {
          const char* src = xrow + c * 128 + ((g ^ (c & 7)) << 4);
          __builtin_amdgcn_global_load_lds(
              (const __attribute__((address_space(1))) u32*)src,
              (__attribute__((address_space(3))) u32*)(rowbase + it * 1024),
              16, 0, 0);                      // HW adds lane*16
        } else {
          u32x4 z = {0u, 0u, 0u, 0u};
          *(u32x4*)(rowbase + it * 1024 + l * 16) = z;
        }
      }
    } else {                                  // out-of-image row -> zeros
      u32x4 z = {0u, 0u, 0u, 0u};
#pragma unroll
      for (int it = 0; it < 9; ++it)
        *(u32x4*)(rowbase + it * 1024 + l * 16) = z;
    }
  }
  __syncthreads();

  // ---- compute: wave = (oh = o-half, q32 = px quarter, rp = row pair) ----
  int oh = wv >> 2, q32 = (wv >> 1) & 1, rp = wv & 1;
  int l31 = l & 31, lhi = l >> 5;
  f32x16 a0 = 0, a1 = 0;                      // acc[2 rows]
  const u32x4* apb = apv + (size_t)(oh * 64 + l);
  const char* pcol = tile + (size_t)rp * 2 * ROWB + (q32 * 32 + l31) * 128;

#pragma unroll
  for (int dx = 0; dx < 5; ++dx) {
    int c7 = (l31 + dx) & 7;                  // q32*32 doesn't change &7
    const char* pb = pcol + dx * 128;
#pragma unroll
    for (int kc = 0; kc < 4; ++kc) {
      int gx = ((kc * 2 + lhi) ^ c7) << 4;    // swizzled granule offset
      u32x4 br[6];
#pragma unroll
      for (int j = 0; j < 6; ++j) br[j] = *(const u32x4*)(pb + j * ROWB + gx);
      u32x4 af[5];
#pragma unroll
      for (int dy = 0; dy < 5; ++dy)
        af[dy] = apb[(size_t)(dy * 5 + dx) * 512 + kc * 128];
#pragma unroll
      for (int dy = 0; dy < 5; ++dy) {
        bf16x8 A = __builtin_bit_cast(bf16x8, af[dy]);
        a0 = __builtin_amdgcn_mfma_f32_32x32x16_bf16(A, __builtin_bit_cast(bf16x8, br[dy]),     a0, 0, 0, 0);
        a1 = __builtin_amdgcn_mfma_f32_32x32x16_bf16(A, __builtin_bit_cast(bf16x8, br[dy + 1]), a1, 0, 0, 0);
      }
    }
  }

  // ---- epilogue: C/D layout col=lane&31, row=(rg&3)+8*(rg>>2)+4*(lane>>5)
  float* ob = out + ((size_t)(n * 64 + oh * 32) * 128 + (y0 + rp * 2)) * 128
              + px0 + q32 * 32 + l31;
#pragma unroll
  for (int rg = 0; rg < 16; ++rg) {
    int orow = (rg & 3) + 8 * (rg >> 2) + 4 * lhi;
    float* obr = ob + (size_t)orow * 16384;
    obr[0]   = a0[rg];
    obr[128] = a1[rg];
  }
}

extern "C" void kernel_launch(void* const* d_in, const int* in_sizes, int n_in,
                              void* d_out, int out_size, void* d_ws, size_t ws_size,
                              hipStream_t stream) {
  const float* x     = (const float*)d_in[0];   // (32,64,128,128) fp32
  const float* wgt   = (const float*)d_in[1];   // (64,64,5,5) fp32
  const float* alpha = (const float*)d_in[2];   // (1,) fp32
  float* out = (float*)d_out;

  u16* apack = (u16*)d_ws;                                  // 204800 B
  u16* xt    = (u16*)((char*)d_ws + (1 << 20));             // 64 MiB

  k_prep <<<16,   256, 0, stream>>>(wgt, alpha, apack);
  k_xcast<<<4096, 256, 0, stream>>>(x, xt);
  k_conv <<<2048, 512, 0, stream>>>(xt, (const u32x4*)apack, out);
}

// Round 9
// 140.494 us; speedup vs baseline: 1.0811x; 1.0811x over previous
//
#include <hip/hip_runtime.h>
#include <stdint.h>

typedef __attribute__((ext_vector_type(8))) __bf16 bf16x8;
typedef __attribute__((ext_vector_type(16))) float f32x16;
typedef __attribute__((ext_vector_type(4))) unsigned int u32x4;
typedef __attribute__((ext_vector_type(4))) float f32x4;
typedef unsigned int u32;
typedef unsigned short u16;

#define THETA 0.7f

__host__ __device__ constexpr float pht_val(int q) {
  return (q == 12) ? (-4.0f + 1e-6f)
       : (q == 7 || q == 11 || q == 13 || q == 17) ? (1.0f + 1e-6f)
       : 1e-6f;
}

__device__ __forceinline__ u16 f2bf(float v) {
  u32 u = __builtin_bit_cast(u32, v);
  return (u16)((u + 0x7fffu + ((u >> 16) & 1u)) >> 16);
}

// ---------------- kernel 1: build K_eff, packed as MFMA A-fragments -------
__global__ __launch_bounds__(256) void k_prep(const float* __restrict__ wgt,
                                              const float* __restrict__ alpha,
                                              u16* __restrict__ apack) {
  int t = blockIdx.x * 256 + threadIdx.x;   // 4096 threads: (o, ci)
  int o = t >> 6, ci = t & 63;
  const float* wp = wgt + ((size_t)(o * 64 + ci)) * 25;
  float wv[25], sumw = 0.f;
#pragma unroll
  for (int p = 0; p < 25; ++p) { wv[p] = wp[p]; sumw += wv[p]; }
  float keff[25];
#pragma unroll
  for (int p = 0; p < 25; ++p) keff[p] = pht_val(p) * wv[p];  // a=0 (identity)
  constexpr int TP[33] = {0,1,2,3,4,6,7,9,12,13,  0,1,2,3,4,  0, 0, 0,
                          0,5,10,15,20,  0,5,6,10,11,12,15,17,20,21};
  constexpr int TQ[33] = {5,6,12,17,23,10,16,22,20,21,  0,5,10,15,20,  5, 0, 5,
                          0,6,7,8,9,  5,6,2,12,8,4,17,9,23,14};
#pragma unroll
  for (int e = 0; e < 33; ++e) keff[TP[e]] += pht_val(TQ[e]) * wv[TQ[e]];

  float al = alpha[0];
  int kc = ci >> 4, oh = o >> 5;
  int lane = ((ci >> 3) & 1) * 32 + (o & 31);   // A-frag: lane=(k/8)*32+m
#pragma unroll
  for (int p = 0; p < 25; ++p) {
    float v = al * (keff[p] * 0.125f);
    if (p == 12) v -= THETA * sumw;             // fold 1x1 branch into center
    size_t idx = ((((size_t)p * 4 + kc) * 2 + oh) * 64 + lane) * 8 + (ci & 7);
    apack[idx] = f2bf(v);
  }
}

// ---------------- kernel 2: x (NCHW fp32) -> X_t[n][y][px][i] bf16 --------
__global__ __launch_bounds__(256) void k_xcast(const float* __restrict__ x,
                                               u16* __restrict__ xt) {
  __shared__ u16 lt[64][130];
  int bid = blockIdx.x;                       // n*128 + y
  int n = bid >> 7, y = bid & 127;
  const float* xb = x + (size_t)n * 64 * 16384 + (size_t)y * 128;
  int t = threadIdx.x;
#pragma unroll
  for (int it = 0; it < 8; ++it) {            // float4 reads
    int idx = it * 256 + t;
    int i = idx >> 5, p4 = (idx & 31) * 4;
    f32x4 v = *(const f32x4*)(xb + (size_t)i * 16384 + p4);
    lt[i][p4 + 0] = f2bf(v.x); lt[i][p4 + 1] = f2bf(v.y);
    lt[i][p4 + 2] = f2bf(v.z); lt[i][p4 + 3] = f2bf(v.w);
  }
  __syncthreads();
  u32* xtb = (u32*)(xt + (size_t)(n * 128 + y) * 8192);
#pragma unroll
  for (int it = 0; it < 16; ++it) {           // u32 writes (2 i per lane)
    int idx = it * 256 + t;
    int px = idx >> 5, i2 = idx & 31;
    u32 w = (u32)lt[2 * i2][px] | ((u32)lt[2 * i2 + 1][px] << 16);
    xtb[(size_t)px * 32 + i2] = w;
  }
}

// ---------------- kernel 3: conv via 32x32x16 bf16 MFMA -------------------
// R6 geometry (4 rows x 64 px x 64 o, 72 KB tile, 4 waves, 2 blocks/CU).
// NEW: fully-unrolled software pipeline. Each of the 20 (dx,kc) iterations
// issues NEXT iteration's 8 ds_read + 5 A-loads, then runs the current
// 20-MFMA burst; sched_group_barrier chains force {VMEM x5, (DS x2,
// MFMA x5) x4} per iteration so LDS/VMEM issue UNDER the MFMA burst.
// (R6/R8 counters showed pipes alternating: serial sum of MFMA 43us +
// LDS 34us + stores 21us ~= dur. MfmaUtil ~43%.)
#define ROWB 9216

#define MM(A, B, C) __builtin_amdgcn_mfma_f32_32x32x16_bf16((A), __builtin_bit_cast(bf16x8, (B)), (C), 0, 0, 0)

#define LDBR(S, DX, KC) do {                                                \
    const char* pb_ = pcol + (DX) * 128;                                    \
    int gx_ = ((((KC) * 2 + lhi) ^ ((l31 + (DX)) & 7)) << 4);               \
    br##S##0 = *(const u32x4*)(pb_ + 0 * ROWB + gx_);                       \
    br##S##1 = *(const u32x4*)(pb_ + 1 * ROWB + gx_);                       \
    br##S##2 = *(const u32x4*)(pb_ + 2 * ROWB + gx_);                       \
    br##S##3 = *(const u32x4*)(pb_ + 3 * ROWB + gx_);                       \
    br##S##4 = *(const u32x4*)(pb_ + 4 * ROWB + gx_);                       \
    br##S##5 = *(const u32x4*)(pb_ + 5 * ROWB + gx_);                       \
    br##S##6 = *(const u32x4*)(pb_ + 6 * ROWB + gx_);                       \
    br##S##7 = *(const u32x4*)(pb_ + 7 * ROWB + gx_);                       \
  } while (0)

#define LDAF(S, DX, KC) do {                                                \
    af##S##0 = apb[(size_t)((0 * 5 + (DX)) * 512 + (KC) * 128)];            \
    af##S##1 = apb[(size_t)((1 * 5 + (DX)) * 512 + (KC) * 128)];            \
    af##S##2 = apb[(size_t)((2 * 5 + (DX)) * 512 + (KC) * 128)];            \
    af##S##3 = apb[(size_t)((3 * 5 + (DX)) * 512 + (KC) * 128)];            \
    af##S##4 = apb[(size_t)((4 * 5 + (DX)) * 512 + (KC) * 128)];            \
  } while (0)

#define BURST(S) do {                                                       \
    bf16x8 A_;                                                              \
    A_ = __builtin_bit_cast(bf16x8, af##S##0);                              \
    a0 = MM(A_, br##S##0, a0); a1 = MM(A_, br##S##1, a1);                   \
    a2 = MM(A_, br##S##2, a2); a3 = MM(A_, br##S##3, a3);                   \
    A_ = __builtin_bit_cast(bf16x8, af##S##1);                              \
    a0 = MM(A_, br##S##1, a0); a1 = MM(A_, br##S##2, a1);                   \
    a2 = MM(A_, br##S##3, a2); a3 = MM(A_, br##S##4, a3);                   \
    A_ = __builtin_bit_cast(bf16x8, af##S##2);                              \
    a0 = MM(A_, br##S##2, a0); a1 = MM(A_, br##S##3, a1);                   \
    a2 = MM(A_, br##S##4, a2); a3 = MM(A_, br##S##5, a3);                   \
    A_ = __builtin_bit_cast(bf16x8, af##S##3);                              \
    a0 = MM(A_, br##S##3, a0); a1 = MM(A_, br##S##4, a1);                   \
    a2 = MM(A_, br##S##5, a2); a3 = MM(A_, br##S##6, a3);                   \
    A_ = __builtin_bit_cast(bf16x8, af##S##4);                              \
    a0 = MM(A_, br##S##4, a0); a1 = MM(A_, br##S##5, a1);                   \
    a2 = MM(A_, br##S##6, a2); a3 = MM(A_, br##S##7, a3);                   \
  } while (0)

#define SGB __builtin_amdgcn_sched_group_barrier
#define SCHED_FULL() do {                                                   \
    SGB(0x020, 5, 0);              /* 5 VMEM (next af) early */             \
    SGB(0x100, 2, 0); SGB(0x008, 5, 0);                                     \
    SGB(0x100, 2, 0); SGB(0x008, 5, 0);                                     \
    SGB(0x100, 2, 0); SGB(0x008, 5, 0);                                     \
    SGB(0x100, 2, 0); SGB(0x008, 5, 0);                                     \
  } while (0)

#define ITER(CUR, NXT, DXN, KCN) do {                                       \
    LDBR(NXT, DXN, KCN); LDAF(NXT, DXN, KCN); BURST(CUR); SCHED_FULL();     \
  } while (0)

__global__ __launch_bounds__(256, 2) void k_conv(const u16* __restrict__ xt,
                                                 const u32x4* __restrict__ apv,
                                                 float* __restrict__ out) {
  __shared__ char tile[8 * ROWB];             // 73728 B
  int bid = blockIdx.x;
  int lg = (bid & 7) * 256 + (bid >> 3);      // XCD swizzle (2048%8==0)
  int ph = lg & 1, yt = (lg >> 1) & 31, n = lg >> 6;
  int y0 = yt * 4, px0 = ph * 64;
  int tid = threadIdx.x;
  int l = tid & 63, wv = tid >> 6;            // 4 waves

  // ---- stage: wave wv stages tile rows 2wv, 2wv+1 (pre-swizzled source) ----
#pragma unroll
  for (int rr = 0; rr < 2; ++rr) {
    int r = 2 * wv + rr;
    int sy = y0 + r - 2;
    char* rowbase = tile + r * ROWB;
    if ((unsigned)sy < 128u) {
      // row byte base shifted so tile col c holds src px = px0 + c - 2
      const char* xrow = (const char*)xt + ((size_t)(n * 128 + sy) * 16384)
                         + (ptrdiff_t)(px0 - 2) * 128;
      int g = l & 7;
#pragma unroll
      for (int it = 0; it < 9; ++it) {        // 576 granule slots >= 544+pad
        int gi = it * 64 + l;
        int c = gi >> 3;
        bool valid = ((unsigned)(px0 + c - 2) < 128u) && (c < 68);
        if (valid) {
          const char* src = xrow + c * 128 + ((g ^ (c & 7)) << 4);
          __builtin_amdgcn_global_load_lds(
              (const __attribute__((address_space(1))) u32*)src,
              (__attribute__((address_space(3))) u32*)(rowbase + it * 1024),
              16, 0, 0);                      // HW adds lane*16
        } else {
          u32x4 z = {0u, 0u, 0u, 0u};
          *(u32x4*)(rowbase + it * 1024 + l * 16) = z;
        }
      }
    } else {                                  // out-of-image row -> zeros
      u32x4 z = {0u, 0u, 0u, 0u};
#pragma unroll
      for (int it = 0; it < 9; ++it)
        *(u32x4*)(rowbase + it * 1024 + l * 16) = z;
    }
  }

  // ---- compute: wave = (oh = o-half, q32 = px quarter), all 4 rows ----
  int oh = wv >> 1, q32 = wv & 1;
  int l31 = l & 31, lhi = l >> 5;
  const u32x4* apb = apv + (size_t)(oh * 64 + l);
  const char* pcol = tile + (q32 * 32 + l31) * 128;

  u32x4 brA0, brA1, brA2, brA3, brA4, brA5, brA6, brA7;
  u32x4 brB0, brB1, brB2, brB3, brB4, brB5, brB6, brB7;
  u32x4 afA0, afA1, afA2, afA3, afA4;
  u32x4 afB0, afB1, afB2, afB3, afB4;

  LDAF(A, 0, 0);                              // iter-0 A-frags hide under
  __syncthreads();                            // the stage drain
  LDBR(A, 0, 0);

  f32x16 a0 = 0, a1 = 0, a2 = 0, a3 = 0;      // acc[row]

  // 20 iterations, (dx outer, kc inner), alternating register sets
  ITER(A, B, 0, 1);
  ITER(B, A, 0, 2);
  ITER(A, B, 0, 3);
  ITER(B, A, 1, 0);
  ITER(A, B, 1, 1);
  ITER(B, A, 1, 2);
  ITER(A, B, 1, 3);
  ITER(B, A, 2, 0);
  ITER(A, B, 2, 1);
  ITER(B, A, 2, 2);
  ITER(A, B, 2, 3);
  ITER(B, A, 3, 0);
  ITER(A, B, 3, 1);
  ITER(B, A, 3, 2);
  ITER(A, B, 3, 3);
  ITER(B, A, 4, 0);
  ITER(A, B, 4, 1);
  ITER(B, A, 4, 2);
  ITER(A, B, 4, 3);
  BURST(B);                                   // last iteration, no prefetch

  // ---- epilogue: C/D layout col=lane&31, row=(rg&3)+8*(rg>>2)+4*(lane>>5)
  float* ob = out + ((size_t)(n * 64 + oh * 32) * 128 + y0) * 128
              + px0 + q32 * 32 + l31;
#pragma unroll
  for (int rg = 0; rg < 16; ++rg) {
    int orow = (rg & 3) + 8 * (rg >> 2) + 4 * lhi;
    float* obr = ob + (size_t)orow * 16384;
    obr[0]   = a0[rg];
    obr[128] = a1[rg];
    obr[256] = a2[rg];
    obr[384] = a3[rg];
  }
}

extern "C" void kernel_launch(void* const* d_in, const int* in_sizes, int n_in,
                              void* d_out, int out_size, void* d_ws, size_t ws_size,
                              hipStream_t stream) {
  const float* x     = (const float*)d_in[0];   // (32,64,128,128) fp32
  const float* wgt   = (const float*)d_in[1];   // (64,64,5,5) fp32
  const float* alpha = (const float*)d_in[2];   // (1,) fp32
  float* out = (float*)d_out;

  u16* apack = (u16*)d_ws;                                  // 204800 B
  u16* xt    = (u16*)((char*)d_ws + (1 << 20));             // 64 MiB

  k_prep <<<16,   256, 0, stream>>>(wgt, alpha, apack);
  k_xcast<<<4096, 256, 0, stream>>>(x, xt);
  k_conv <<<2048, 256, 0, stream>>>(xt, (const u32x4*)apack, out);
}

// Round 10
// 126.653 us; speedup vs baseline: 1.1992x; 1.1093x over previous
//
#include <hip/hip_runtime.h>
#include <stdint.h>

typedef __attribute__((ext_vector_type(8))) __bf16 bf16x8;
typedef __attribute__((ext_vector_type(16))) float f32x16;
typedef __attribute__((ext_vector_type(4))) unsigned int u32x4;
typedef __attribute__((ext_vector_type(2))) float f32x2;
typedef unsigned int u32;
typedef unsigned short u16;

#define THETA 0.7f

__host__ __device__ constexpr float pht_val(int q) {
  return (q == 12) ? (-4.0f + 1e-6f)
       : (q == 7 || q == 11 || q == 13 || q == 17) ? (1.0f + 1e-6f)
       : 1e-6f;
}

__device__ __forceinline__ u16 f2bf(float v) {
  u32 u = __builtin_bit_cast(u32, v);
  return (u16)((u + 0x7fffu + ((u >> 16) & 1u)) >> 16);
}

// ---------------- kernel 1: build K_eff, packed as MFMA A-fragments -------
__global__ __launch_bounds__(256) void k_prep(const float* __restrict__ wgt,
                                              const float* __restrict__ alpha,
                                              u16* __restrict__ apack) {
  int t = blockIdx.x * 256 + threadIdx.x;   // 4096 threads: (o, ci)
  int o = t >> 6, ci = t & 63;
  const float* wp = wgt + ((size_t)(o * 64 + ci)) * 25;
  float wv[25], sumw = 0.f;
#pragma unroll
  for (int p = 0; p < 25; ++p) { wv[p] = wp[p]; sumw += wv[p]; }
  float keff[25];
#pragma unroll
  for (int p = 0; p < 25; ++p) keff[p] = pht_val(p) * wv[p];  // a=0 (identity)
  constexpr int TP[33] = {0,1,2,3,4,6,7,9,12,13,  0,1,2,3,4,  0, 0, 0,
                          0,5,10,15,20,  0,5,6,10,11,12,15,17,20,21};
  constexpr int TQ[33] = {5,6,12,17,23,10,16,22,20,21,  0,5,10,15,20,  5, 0, 5,
                          0,6,7,8,9,  5,6,2,12,8,4,17,9,23,14};
#pragma unroll
  for (int e = 0; e < 33; ++e) keff[TP[e]] += pht_val(TQ[e]) * wv[TQ[e]];

  float al = alpha[0];
  int kc = ci >> 4, oh = o >> 5;
  int lane = ((ci >> 3) & 1) * 32 + (o & 31);   // A-frag: lane=(k/8)*32+m
#pragma unroll
  for (int p = 0; p < 25; ++p) {
    float v = al * (keff[p] * 0.125f);
    if (p == 12) v -= THETA * sumw;             // fold 1x1 branch into center
    size_t idx = ((((size_t)p * 4 + kc) * 2 + oh) * 64 + lane) * 8 + (ci & 7);
    apack[idx] = f2bf(v);
  }
}

// ---------------- kernel 2: FUSED conv (cast+stage+MFMA) ------------------
// R9 compute loop/epilogue verbatim. Stage replaced: read x fp32 directly,
// convert to bf16 in-register, write swizzled tile (kills the separate
// xcast pass: 192 MB of HBM round-trips + a serial kernel).
#define ROWB 9216

#define MM(A, B, C) __builtin_amdgcn_mfma_f32_32x32x16_bf16((A), __builtin_bit_cast(bf16x8, (B)), (C), 0, 0, 0)

#define LDBR(S, DX, KC) do {                                                \
    const char* pb_ = pcol + (DX) * 128;                                    \
    int gx_ = ((((KC) * 2 + lhi) ^ ((l31 + (DX)) & 7)) << 4);               \
    br##S##0 = *(const u32x4*)(pb_ + 0 * ROWB + gx_);                       \
    br##S##1 = *(const u32x4*)(pb_ + 1 * ROWB + gx_);                       \
    br##S##2 = *(const u32x4*)(pb_ + 2 * ROWB + gx_);                       \
    br##S##3 = *(const u32x4*)(pb_ + 3 * ROWB + gx_);                       \
    br##S##4 = *(const u32x4*)(pb_ + 4 * ROWB + gx_);                       \
    br##S##5 = *(const u32x4*)(pb_ + 5 * ROWB + gx_);                       \
    br##S##6 = *(const u32x4*)(pb_ + 6 * ROWB + gx_);                       \
    br##S##7 = *(const u32x4*)(pb_ + 7 * ROWB + gx_);                       \
  } while (0)

#define LDAF(S, DX, KC) do {                                                \
    af##S##0 = apb[(size_t)((0 * 5 + (DX)) * 512 + (KC) * 128)];            \
    af##S##1 = apb[(size_t)((1 * 5 + (DX)) * 512 + (KC) * 128)];            \
    af##S##2 = apb[(size_t)((2 * 5 + (DX)) * 512 + (KC) * 128)];            \
    af##S##3 = apb[(size_t)((3 * 5 + (DX)) * 512 + (KC) * 128)];            \
    af##S##4 = apb[(size_t)((4 * 5 + (DX)) * 512 + (KC) * 128)];            \
  } while (0)

#define BURST(S) do {                                                       \
    bf16x8 A_;                                                              \
    A_ = __builtin_bit_cast(bf16x8, af##S##0);                              \
    a0 = MM(A_, br##S##0, a0); a1 = MM(A_, br##S##1, a1);                   \
    a2 = MM(A_, br##S##2, a2); a3 = MM(A_, br##S##3, a3);                   \
    A_ = __builtin_bit_cast(bf16x8, af##S##1);                              \
    a0 = MM(A_, br##S##1, a0); a1 = MM(A_, br##S##2, a1);                   \
    a2 = MM(A_, br##S##3, a2); a3 = MM(A_, br##S##4, a3);                   \
    A_ = __builtin_bit_cast(bf16x8, af##S##2);                              \
    a0 = MM(A_, br##S##2, a0); a1 = MM(A_, br##S##3, a1);                   \
    a2 = MM(A_, br##S##4, a2); a3 = MM(A_, br##S##5, a3);                   \
    A_ = __builtin_bit_cast(bf16x8, af##S##3);                              \
    a0 = MM(A_, br##S##3, a0); a1 = MM(A_, br##S##4, a1);                   \
    a2 = MM(A_, br##S##5, a2); a3 = MM(A_, br##S##6, a3);                   \
    A_ = __builtin_bit_cast(bf16x8, af##S##4);                              \
    a0 = MM(A_, br##S##4, a0); a1 = MM(A_, br##S##5, a1);                   \
    a2 = MM(A_, br##S##6, a2); a3 = MM(A_, br##S##7, a3);                   \
  } while (0)

#define SGB __builtin_amdgcn_sched_group_barrier
#define SCHED_FULL() do {                                                   \
    SGB(0x020, 5, 0);              /* 5 VMEM (next af) early */             \
    SGB(0x100, 2, 0); SGB(0x008, 5, 0);                                     \
    SGB(0x100, 2, 0); SGB(0x008, 5, 0);                                     \
    SGB(0x100, 2, 0); SGB(0x008, 5, 0);                                     \
    SGB(0x100, 2, 0); SGB(0x008, 5, 0);                                     \
  } while (0)

#define ITER(CUR, NXT, DXN, KCN) do {                                       \
    LDBR(NXT, DXN, KCN); LDAF(NXT, DXN, KCN); BURST(CUR); SCHED_FULL();     \
  } while (0)

// swizzled write: col c, ch-pair i2 -> byte offset in a tile row
#define TWR(RB, C, I2, W)                                                   \
  *(u32*)((RB) + (C) * 128 + ((((I2) >> 2) ^ ((C) & 7)) << 4)               \
          + (((I2) & 3) << 2)) = (W)

__global__ __launch_bounds__(256, 2) void k_conv(const float* __restrict__ x,
                                                 const u32x4* __restrict__ apv,
                                                 float* __restrict__ out) {
  __shared__ char tile[8 * ROWB];             // 73728 B
  int bid = blockIdx.x;
  int lg = (bid & 7) * 256 + (bid >> 3);      // XCD swizzle (2048%8==0)
  int ph = lg & 1, yt = (lg >> 1) & 31, n = lg >> 6;
  int y0 = yt * 4, px0 = ph * 64;
  int tid = threadIdx.x;
  int l = tid & 63;

  // ---- fused stage: x fp32 -> bf16 -> swizzled tile[r][c][i] ----
  // col c holds src px = px0 + c - 2; ch i at (pre-swizzle) byte i*2.
  {
    const float* xn = x + (size_t)n * 64 * 16384;
    int p = tid & 31;                         // interior px-pair (c = 2p+2)
    int i2g = tid >> 5;                       // ch-pair group
    bool hthr = (tid < 128) && !(tid & 2);    // 64 halo threads
    int hi2 = tid >> 2, hp = tid & 1;
    int hpx = hp ? px0 + 64 : px0 - 2;
    int hc = hp ? 66 : 0;
    bool hvalid = (unsigned)hpx < 128u;
#pragma unroll
    for (int rr = 0; rr < 8; ++rr) {
      int sy = y0 + rr - 2;
      bool rowok = (unsigned)sy < 128u;
      char* rowbase = tile + rr * ROWB;
      const float* xr = xn + (size_t)sy * 128;
#pragma unroll
      for (int m = 0; m < 4; ++m) {
        int i2 = i2g * 4 + m;                 // ch pair (2i2, 2i2+1)
        f32x2 va = {0.f, 0.f}, vb = {0.f, 0.f};
        if (rowok) {
          const float* pa = xr + (size_t)(2 * i2) * 16384 + px0 + 2 * p;
          va = *(const f32x2*)pa;
          vb = *(const f32x2*)(pa + 16384);
        }
        u32 w0 = (u32)f2bf(va.x) | ((u32)f2bf(vb.x) << 16);  // px0+2p
        u32 w1 = (u32)f2bf(va.y) | ((u32)f2bf(vb.y) << 16);  // px0+2p+1
        int c0 = 2 * p + 2;
        TWR(rowbase, c0, i2, w0);
        TWR(rowbase, c0 + 1, i2, w1);
      }
      if (hthr) {                             // halo cols {0,1,66,67}
        f32x2 va = {0.f, 0.f}, vb = {0.f, 0.f};
        if (rowok && hvalid) {
          const float* pa = xr + (size_t)(2 * hi2) * 16384 + hpx;
          va = *(const f32x2*)pa;
          vb = *(const f32x2*)(pa + 16384);
        }
        u32 w0 = (u32)f2bf(va.x) | ((u32)f2bf(vb.x) << 16);
        u32 w1 = (u32)f2bf(va.y) | ((u32)f2bf(vb.y) << 16);
        TWR(rowbase, hc, hi2, w0);
        TWR(rowbase, hc + 1, hi2, w1);
      }
    }
  }

  // ---- compute: wave = (oh = o-half, q32 = px quarter), all 4 rows ----
  int wv = tid >> 6;
  int oh = wv >> 1, q32 = wv & 1;
  int l31 = l & 31, lhi = l >> 5;
  const u32x4* apb = apv + (size_t)(oh * 64 + l);
  const char* pcol = tile + (q32 * 32 + l31) * 128;

  u32x4 brA0, brA1, brA2, brA3, brA4, brA5, brA6, brA7;
  u32x4 brB0, brB1, brB2, brB3, brB4, brB5, brB6, brB7;
  u32x4 afA0, afA1, afA2, afA3, afA4;
  u32x4 afB0, afB1, afB2, afB3, afB4;

  LDAF(A, 0, 0);                              // iter-0 A-frags hide under
  __syncthreads();                            // the stage drain
  LDBR(A, 0, 0);

  f32x16 a0 = 0, a1 = 0, a2 = 0, a3 = 0;      // acc[row]

  // 20 iterations, (dx outer, kc inner), alternating register sets
  ITER(A, B, 0, 1);
  ITER(B, A, 0, 2);
  ITER(A, B, 0, 3);
  ITER(B, A, 1, 0);
  ITER(A, B, 1, 1);
  ITER(B, A, 1, 2);
  ITER(A, B, 1, 3);
  ITER(B, A, 2, 0);
  ITER(A, B, 2, 1);
  ITER(B, A, 2, 2);
  ITER(A, B, 2, 3);
  ITER(B, A, 3, 0);
  ITER(A, B, 3, 1);
  ITER(B, A, 3, 2);
  ITER(A, B, 3, 3);
  ITER(B, A, 4, 0);
  ITER(A, B, 4, 1);
  ITER(B, A, 4, 2);
  ITER(A, B, 4, 3);
  BURST(B);                                   // last iteration, no prefetch

  // ---- epilogue: C/D layout col=lane&31, row=(rg&3)+8*(rg>>2)+4*(lane>>5)
  float* ob = out + ((size_t)(n * 64 + oh * 32) * 128 + y0) * 128
              + px0 + q32 * 32 + l31;
#pragma unroll
  for (int rg = 0; rg < 16; ++rg) {
    int orow = (rg & 3) + 8 * (rg >> 2) + 4 * lhi;
    float* obr = ob + (size_t)orow * 16384;
    obr[0]   = a0[rg];
    obr[128] = a1[rg];
    obr[256] = a2[rg];
    obr[384] = a3[rg];
  }
}

extern "C" void kernel_launch(void* const* d_in, const int* in_sizes, int n_in,
                              void* d_out, int out_size, void* d_ws, size_t ws_size,
                              hipStream_t stream) {
  const float* x     = (const float*)d_in[0];   // (32,64,128,128) fp32
  const float* wgt   = (const float*)d_in[1];   // (64,64,5,5) fp32
  const float* alpha = (const float*)d_in[2];   // (1,) fp32
  float* out = (float*)d_out;

  u16* apack = (u16*)d_ws;                      // 204800 B

  k_prep<<<16,   256, 0, stream>>>(wgt, alpha, apack);
  k_conv<<<2048, 256, 0, stream>>>(x, (const u32x4*)apack, out);
}